// Round 8
// baseline (260.824 us; speedup 1.0000x reference)
//
#include <hip/hip_runtime.h>
#include <math.h>

// Problem constants
#define BATCH 64
#define HH 512
#define WW 512
#define PAD 15
#define NELEM ((size_t)BATCH * HH * WW)
#define INV_KK (1.0f / 961.0f)

#define TILE_H 16              // rows per block (4 iters x 4 rows)
#define BPI (HH / TILE_H)      // 32 blocks per image
#define NBLK (BATCH * BPI)     // 2048 blocks -> 8 blocks/CU
#define NXCD 8

// Padded LDS index: +4 words per 32-word group. Kills the 16-way bank
// conflict on b128 reads at stride 8*lane (R3: 786K conflicts) while keeping
// 16B alignment (8L and pad are both 16B multiples). Max PIDX(511)=571 < 576.
#define PIDX(i) ((i) + ((((i) >> 5)) << 2))
#define PROW 576

typedef float f4 __attribute__((ext_vector_type(4)));

__device__ __forceinline__ float wave_reduce(float v) {
    #pragma unroll
    for (int off = 32; off; off >>= 1) v += __shfl_down(v, off, 64);
    return v;
}

// ---------------------------------------------------------------------------
// Fused kernel. Block = 256 threads (4 waves) owns TILE_H=16 rows of one
// image. Per 4-row iteration:
//   producer: every thread slides rolling vertical 31-sums for its 2 columns
//             (c, c+256) and writes 4 rows into padded LDS      [barrier]
//   scan:     wave wv scans row wv IN PLACE (b128 loads, 8-elem local prefix,
//             6-step wave shuffle scan, b128 writeback) — wave-private, no
//             barrier needed before consuming
//   loss:     lane owns cols 8L..8L+7; window S = P[w+15]-P[w-16] via 2 padded
//             b32 LDS reads/elem; f4 mask/pred loads; accumulate  [barrier]
// Register budget kept tiny (S from LDS, not regs) so (256,8) -> VGPR<=64 ->
// 32 waves/CU with the 2048-block grid (8 blocks/CU).
// ---------------------------------------------------------------------------
__global__ __launch_bounds__(256, 8) void fused_kernel(const float* __restrict__ pred,
                                                       const float* __restrict__ mask,
                                                       double* __restrict__ partials) {
    __shared__ float vrow[4][PROW];
    __shared__ float red[3][4];

    // XCD swizzle: xcd = f%8 (HW round-robin); each XCD owns 8 whole images.
    const int f    = blockIdx.x;
    const int xcd  = f & (NXCD - 1);
    const int slot = f >> 3;               // 0..255
    const int img  = xcd * 8 + (slot >> 5);
    const int tile = slot & (BPI - 1);

    const int tid  = threadIdx.x;
    const int lane = tid & 63;
    const int wv   = tid >> 6;
    const int h0   = tile * TILE_H;        // block's first output row (max 496)
    const int c0   = tid;                  // producer columns
    const int c1   = tid + 256;
    const int cl   = lane * 8;             // loss-phase columns (8 contiguous)

    const float* mb = mask + (size_t)img * HH * WW;
    const float* pb = pred + (size_t)img * HH * WW;

    // --- init rolling vertical window for row h0: rows [max(0,h0-15), min(511,h0+15)]
    float r0 = 0.f, r1 = 0.f;
    {
        int lo = h0 - PAD; if (lo < 0) lo = 0;
        int hi = h0 + PAD; if (hi > HH - 1) hi = HH - 1;
        for (int y = lo; y <= hi; ++y) {
            r0 += mb[(size_t)y * WW + c0];
            r1 += mb[(size_t)y * WW + c1];
        }
    }

    float accb = 0.f, acci = 0.f, accu = 0.f;

    for (int it = 0; it < TILE_H / 4; ++it) {
        const int hbase = h0 + it * 4;

        // --- producer: emit vertical-sum rows hbase..hbase+3, slide window ---
        #pragma unroll
        for (int j = 0; j < 4; ++j) {
            const int h = hbase + j;
            vrow[j][PIDX(c0)] = r0;
            vrow[j][PIDX(c1)] = r1;
            const int add = h + PAD + 1;
            const int sub = h - PAD;
            float a0 = 0.f, a1 = 0.f, s0 = 0.f, s1 = 0.f;
            if (add < HH) { a0 = mb[(size_t)add * WW + c0]; a1 = mb[(size_t)add * WW + c1]; }
            if (sub >= 0) { s0 = mb[(size_t)sub * WW + c0]; s1 = mb[(size_t)sub * WW + c1]; }
            r0 += a0 - s0;
            r1 += a1 - s1;
        }
        __syncthreads();   // vrow rows visible to all waves

        // --- scan: wave wv prefix-scans its own row IN PLACE ---
        {
            const f4 va = *(const f4*)&vrow[wv][PIDX(8 * lane)];
            const f4 vb = *(const f4*)&vrow[wv][PIDX(8 * lane + 4)];
            const float p0 = va.x;
            const float p1 = p0 + va.y;
            const float p2 = p1 + va.z;
            const float p3 = p2 + va.w;
            const float p4 = p3 + vb.x;
            const float p5 = p4 + vb.y;
            const float p6 = p5 + vb.z;
            const float p7 = p6 + vb.w;
            float incl = p7;
            #pragma unroll
            for (int off = 1; off < 64; off <<= 1) {
                float n = __shfl_up(incl, off, 64);
                if (lane >= off) incl += n;
            }
            const float excl = incl - p7;
            f4 Pa, Pb;
            Pa.x = excl + p0; Pa.y = excl + p1; Pa.z = excl + p2; Pa.w = excl + p3;
            Pb.x = excl + p4; Pb.y = excl + p5; Pb.z = excl + p6; Pb.w = excl + p7;
            *(f4*)&vrow[wv][PIDX(8 * lane)]     = Pa;
            *(f4*)&vrow[wv][PIDX(8 * lane + 4)] = Pb;
            // wave-private row: same-wave DS ordering + compiler lgkmcnt make
            // the in-place prefix visible to this wave without a barrier.
        }

        // --- loss: lane owns w = cl..cl+7 of row hbase+wv ---
        {
            const int h = hbase + wv;
            const size_t rb = (size_t)h * WW;
            const f4 mc0 = *(const f4*)&mb[rb + cl];
            const f4 mc1 = *(const f4*)&mb[rb + cl + 4];
            const f4 pc0 = *(const f4*)&pb[rb + cl];
            const f4 pc1 = *(const f4*)&pb[rb + cl + 4];
            const float mm[8] = {mc0.x, mc0.y, mc0.z, mc0.w, mc1.x, mc1.y, mc1.z, mc1.w};
            const float pp[8] = {pc0.x, pc0.y, pc0.z, pc0.w, pc1.x, pc1.y, pc1.z, pc1.w};

            #pragma unroll
            for (int k = 0; k < 8; ++k) {
                const int w = cl + k;
                const int hiw = (w + PAD > WW - 1) ? (WW - 1) : (w + PAD);
                float S = vrow[wv][PIDX(hiw)];
                if (w >= PAD + 1) S -= vrow[wv][PIDX(w - PAD - 1)];

                const float m  = mm[k];
                const float pr = pp[k];
                const float weit = 1.0f + 5.0f * fabsf(S * INV_KK - m);
                const float e    = __expf(-fabsf(pr));
                const float bce  = fmaxf(pr, 0.f) - pr * m + __logf(1.0f + e);
                const float inv  = __builtin_amdgcn_rcpf(1.0f + e);
                const float p    = (pr >= 0.f) ? inv : e * inv;   // sigmoid
                accb += bce;
                acci += p * m * weit;
                accu += (p + m) * weit;
            }
        }
        __syncthreads();   // all waves done reading vrow before next overwrite
    }

    // --- block reduction ---
    accb = wave_reduce(accb);
    acci = wave_reduce(acci);
    accu = wave_reduce(accu);
    if (lane == 0) { red[0][wv] = accb; red[1][wv] = acci; red[2][wv] = accu; }
    __syncthreads();
    if (tid == 0) {
        double bt = (double)red[0][0] + red[0][1] + red[0][2] + red[0][3];
        double it2 = (double)red[1][0] + red[1][1] + red[1][2] + red[1][3];
        double ut = (double)red[2][0] + red[2][1] + red[2][2] + red[2][3];
        const size_t pidx = (size_t)img * BPI + tile;
        partials[pidx * 3 + 0] = bt;
        partials[pidx * 3 + 1] = it2;
        partials[pidx * 3 + 2] = ut;
    }
}

// ---------------------------------------------------------------------------
// Finalize from per-block partials (indexed img*BPI + tile), NBLK = 2048.
// ---------------------------------------------------------------------------
__global__ __launch_bounds__(256) void finalize_kernel(const double* __restrict__ partials,
                                                       float* __restrict__ out) {
    __shared__ double redbce[4];
    int tid = threadIdx.x, lane = tid & 63, wv = tid >> 6;

    double bsum = 0.0;
    for (int i = tid; i < NBLK; i += 256) bsum += partials[(size_t)i * 3 + 0];
    #pragma unroll
    for (int off = 32; off; off >>= 1) bsum += __shfl_down(bsum, off, 64);
    if (lane == 0) redbce[wv] = bsum;
    __syncthreads();

    double wiou_term = 0.0;
    if (tid < 64) {
        int bb = tid;
        double it = 0.0, ut = 0.0;
        for (int j = 0; j < BPI; ++j) {
            it += partials[(size_t)(bb * BPI + j) * 3 + 1];
            ut += partials[(size_t)(bb * BPI + j) * 3 + 2];
        }
        wiou_term = 1.0 - (it + 1.0) / (ut - it + 1.0);
    }
    if (wv == 0) {
        #pragma unroll
        for (int off = 32; off; off >>= 1) wiou_term += __shfl_down(wiou_term, off, 64);
    }
    if (tid == 0) {
        double wbce = (redbce[0] + redbce[1] + redbce[2] + redbce[3]) / (double)NELEM;
        out[0] = (float)(wbce + wiou_term * (1.0 / 64.0));
    }
}

// ---------------------------------------------------------------------------
// Fallback path (tiny ws): recompute vertical sums in-kernel + atomics.
// ---------------------------------------------------------------------------
#define ACC_DOUBLES 129
__global__ __launch_bounds__(256) void rowpass_nows_kernel(const float* __restrict__ pred,
                                                           const float* __restrict__ mask,
                                                           double* __restrict__ acc) {
    __shared__ float vrow1[WW];
    __shared__ float red[3][4];
    int b = blockIdx.x / HH;
    int h = blockIdx.x % HH;
    int lo = h - PAD; if (lo < 0) lo = 0;
    int hi = h + PAD; if (hi > HH - 1) hi = HH - 1;
    float s0 = 0.0f, s1 = 0.0f;
    const float* mb = mask + (size_t)b * HH * WW;
    for (int y = lo; y <= hi; ++y) {
        s0 += mb[(size_t)y * WW + threadIdx.x];
        s1 += mb[(size_t)y * WW + threadIdx.x + 256];
    }
    vrow1[threadIdx.x]       = s0;
    vrow1[threadIdx.x + 256] = s1;
    __syncthreads();

    size_t base = ((size_t)b * HH + h) * WW;
    float bce_p = 0.0f, inter_p = 0.0f, uni_p = 0.0f;
    for (int w = threadIdx.x; w < WW; w += 256) {
        int wlo = w - PAD; if (wlo < 0) wlo = 0;
        int whi = w + PAD; if (whi > WW - 1) whi = WW - 1;
        float s = 0.0f;
        for (int k = wlo; k <= whi; ++k) s += vrow1[k];
        float m  = mask[base + w];
        float pr = pred[base + w];
        float weit = 1.0f + 5.0f * fabsf(s * INV_KK - m);
        float e   = expf(-fabsf(pr));
        float bce = fmaxf(pr, 0.0f) - pr * m + log1pf(e);
        float inv = 1.0f / (1.0f + e);
        float p   = (pr >= 0.0f) ? inv : e * inv;
        bce_p += bce; inter_p += p * m * weit; uni_p += (p + m) * weit;
    }
    int lane = threadIdx.x & 63, wvv = threadIdx.x >> 6;
    bce_p = wave_reduce(bce_p); inter_p = wave_reduce(inter_p); uni_p = wave_reduce(uni_p);
    if (lane == 0) { red[0][wvv] = bce_p; red[1][wvv] = inter_p; red[2][wvv] = uni_p; }
    __syncthreads();
    if (threadIdx.x == 0) {
        atomicAdd(&acc[0], (double)(red[0][0] + red[0][1] + red[0][2] + red[0][3]));
        atomicAdd(&acc[1 + b], (double)(red[1][0] + red[1][1] + red[1][2] + red[1][3]));
        atomicAdd(&acc[65 + b], (double)(red[2][0] + red[2][1] + red[2][2] + red[2][3]));
    }
}

__global__ void finalize_atomic_kernel(const double* __restrict__ acc, float* __restrict__ out) {
    int b = threadIdx.x;
    double inter = acc[1 + b];
    double uni   = acc[65 + b];
    double wiou = 1.0 - (inter + 1.0) / (uni - inter + 1.0);
    #pragma unroll
    for (int off = 32; off; off >>= 1) wiou += __shfl_down(wiou, off, 64);
    if (b == 0) {
        double wbce = acc[0] / (double)NELEM;
        out[0] = (float)(wbce + wiou * (1.0 / 64.0));
    }
}

// ---------------------------------------------------------------------------
extern "C" void kernel_launch(void* const* d_in, const int* in_sizes, int n_in,
                              void* d_out, int out_size, void* d_ws, size_t ws_size,
                              hipStream_t stream) {
    const float* pred = (const float*)d_in[0];
    const float* mask = (const float*)d_in[1];
    float* out = (float*)d_out;

    const size_t part_bytes = (size_t)NBLK * 3 * sizeof(double);   // 48 KiB

    if (ws_size >= part_bytes) {
        double* partials = (double*)d_ws;
        fused_kernel<<<NBLK, 256, 0, stream>>>(pred, mask, partials);
        finalize_kernel<<<1, 256, 0, stream>>>(partials, out);
    } else {
        double* acc = (double*)d_ws;
        hipMemsetAsync(acc, 0, ACC_DOUBLES * sizeof(double), stream);
        rowpass_nows_kernel<<<BATCH * HH, 256, 0, stream>>>(pred, mask, acc);
        finalize_atomic_kernel<<<1, 64, 0, stream>>>(acc, out);
    }
}

// Round 9
// 81.529 us; speedup vs baseline: 3.1992x; 3.1992x over previous
//
#include <hip/hip_runtime.h>
#include <math.h>

// Problem constants
#define BATCH 64
#define HH 512
#define WW 512
#define PAD 15
#define NELEM ((size_t)BATCH * HH * WW)
#define INV_KK (1.0f / 961.0f)

#define TILE_H 16              // rows per block (4 iters x 4 rows)
#define BPI (HH / TILE_H)      // 32 blocks per image
#define NBLK (BATCH * BPI)     // 2048 blocks -> 8 blocks/CU
#define NXCD 8

// Conflict-free LDS padding: +1 word per 8. Index i -> i + i/8.
// All access patterns in this kernel become (9*lane + const), and since
// gcd(9,32)=1 the 64 lanes hit each bank exactly twice (2-way = free, m136).
// Max PIDX(511) = 574 < 576.
#define PIDX(i) ((i) + ((i) >> 3))
#define PROW 576

typedef float f4 __attribute__((ext_vector_type(4)));

__device__ __forceinline__ float wave_reduce(float v) {
    #pragma unroll
    for (int off = 32; off; off >>= 1) v += __shfl_down(v, off, 64);
    return v;
}

__device__ __forceinline__ void loss4(const f4 mc, const f4 pc,
                                      float S0, float S1, float S2, float S3,
                                      float& accb, float& acci, float& accu) {
    const float ms[4] = {mc.x, mc.y, mc.z, mc.w};
    const float ps[4] = {pc.x, pc.y, pc.z, pc.w};
    const float Ss[4] = {S0, S1, S2, S3};
    #pragma unroll
    for (int k = 0; k < 4; ++k) {
        const float m  = ms[k];
        const float pr = ps[k];
        const float weit = 1.0f + 5.0f * fabsf(Ss[k] * INV_KK - m);
        const float e    = __expf(-fabsf(pr));
        const float bce  = fmaxf(pr, 0.f) - pr * m + __logf(1.0f + e);
        const float inv  = __builtin_amdgcn_rcpf(1.0f + e);
        const float p    = (pr >= 0.f) ? inv : e * inv;   // sigmoid(pr)
        accb += bce;
        acci += p * m * weit;
        accu += (p + m) * weit;
    }
}

// ---------------------------------------------------------------------------
// Fused kernel. Block = 256 threads (4 waves) owns TILE_H=16 rows of one
// image. Per 4-row iteration:
//   producer: each thread slides rolling vertical 31-sums for cols (tid,
//             tid+256), writes 4 rows into padded LDS            [barrier]
//   scan:     wave wv prefix-scans row wv IN PLACE (b32 ops, contiguous
//             9L..9L+7 per lane; 6-step shuffle scan) — wave-private
//   loss:     lane owns cols 8L..8L+7; S = P[w+15]-P[w-16] via 2 conflict-
//             free b32 reads/elem; two f4 groups to cap live regs [barrier]
// NO min-waves clause: (256,4)/(256,8) capped VGPR at 64/32 and spilled
// 142/437 MB to scratch (R4/R8). Natural allocation fits; grid = 8 blk/CU.
// ---------------------------------------------------------------------------
__global__ __launch_bounds__(256) void fused_kernel(const float* __restrict__ pred,
                                                    const float* __restrict__ mask,
                                                    double* __restrict__ partials) {
    __shared__ float vrow[4][PROW];
    __shared__ float red[3][4];

    // XCD swizzle: xcd = f%8 (HW round-robin); each XCD owns 8 whole images.
    const int f    = blockIdx.x;
    const int xcd  = f & (NXCD - 1);
    const int slot = f >> 3;               // 0..255
    const int img  = xcd * 8 + (slot >> 5);
    const int tile = slot & (BPI - 1);

    const int tid  = threadIdx.x;
    const int lane = tid & 63;
    const int wv   = tid >> 6;
    const int h0   = tile * TILE_H;        // block's first output row (max 496)
    const int c0   = tid;                  // producer columns
    const int c1   = tid + 256;
    const int pc0i = PIDX(c0);
    const int pc1i = PIDX(c1);
    const int cl   = lane * 8;             // loss-phase columns (8 contiguous)
    const int base9 = 9 * lane;            // PIDX(8*lane) = 9*lane, contiguous run

    const float* mb = mask + (size_t)img * HH * WW;
    const float* pb = pred + (size_t)img * HH * WW;

    // --- init rolling vertical window for row h0: rows [max(0,h0-15), min(511,h0+15)]
    float r0 = 0.f, r1 = 0.f;
    {
        int lo = h0 - PAD; if (lo < 0) lo = 0;
        int hi = h0 + PAD; if (hi > HH - 1) hi = HH - 1;
        for (int y = lo; y <= hi; ++y) {
            r0 += mb[(size_t)y * WW + c0];
            r1 += mb[(size_t)y * WW + c1];
        }
    }

    float accb = 0.f, acci = 0.f, accu = 0.f;

    for (int it = 0; it < TILE_H / 4; ++it) {
        const int hbase = h0 + it * 4;

        // --- producer: emit vertical-sum rows hbase..hbase+3, slide window ---
        #pragma unroll
        for (int j = 0; j < 4; ++j) {
            const int h = hbase + j;
            vrow[j][pc0i] = r0;
            vrow[j][pc1i] = r1;
            const int add = h + PAD + 1;
            const int sub = h - PAD;
            float a0 = 0.f, a1 = 0.f, s0 = 0.f, s1 = 0.f;
            if (add < HH) { a0 = mb[(size_t)add * WW + c0]; a1 = mb[(size_t)add * WW + c1]; }
            if (sub >= 0) { s0 = mb[(size_t)sub * WW + c0]; s1 = mb[(size_t)sub * WW + c1]; }
            r0 += a0 - s0;
            r1 += a1 - s1;
        }
        __syncthreads();   // vrow rows visible to all waves

        // --- scan: wave wv prefix-scans its own row IN PLACE (conflict-free) ---
        {
            float* row = vrow[wv];
            const float v0 = row[base9 + 0];
            const float v1 = row[base9 + 1];
            const float v2 = row[base9 + 2];
            const float v3 = row[base9 + 3];
            const float v4 = row[base9 + 4];
            const float v5 = row[base9 + 5];
            const float v6 = row[base9 + 6];
            const float v7 = row[base9 + 7];
            const float p0 = v0;
            const float p1 = p0 + v1;
            const float p2 = p1 + v2;
            const float p3 = p2 + v3;
            const float p4 = p3 + v4;
            const float p5 = p4 + v5;
            const float p6 = p5 + v6;
            const float p7 = p6 + v7;
            float incl = p7;
            #pragma unroll
            for (int off = 1; off < 64; off <<= 1) {
                float n = __shfl_up(incl, off, 64);
                if (lane >= off) incl += n;
            }
            const float excl = incl - p7;
            row[base9 + 0] = excl + p0;
            row[base9 + 1] = excl + p1;
            row[base9 + 2] = excl + p2;
            row[base9 + 3] = excl + p3;
            row[base9 + 4] = excl + p4;
            row[base9 + 5] = excl + p5;
            row[base9 + 6] = excl + p6;
            row[base9 + 7] = excl + p7;
            // wave-private row: same-wave DS ordering makes the in-place
            // prefix visible to this wave without a barrier.
        }

        // --- loss: lane owns w = cl..cl+7 of row hbase+wv ---
        {
            const int h = hbase + wv;
            const size_t rb = (size_t)h * WW;
            const float* row = vrow[wv];

            // window sums first (conflict-free b32 reads), then two f4 groups
            float S0, S1, S2, S3, S4, S5, S6, S7;
            {
                #define WINS(k, dst) { \
                    const int w = cl + (k); \
                    const int hiw = (w + PAD > WW - 1) ? (WW - 1) : (w + PAD); \
                    float s = row[PIDX(hiw)]; \
                    if (w >= PAD + 1) s -= row[PIDX(w - PAD - 1)]; \
                    dst = s; }
                WINS(0, S0) WINS(1, S1) WINS(2, S2) WINS(3, S3)
                WINS(4, S4) WINS(5, S5) WINS(6, S6) WINS(7, S7)
                #undef WINS
            }
            {
                const f4 mc = *(const f4*)&mb[rb + cl];
                const f4 pc = *(const f4*)&pb[rb + cl];
                loss4(mc, pc, S0, S1, S2, S3, accb, acci, accu);
            }
            {
                const f4 mc = *(const f4*)&mb[rb + cl + 4];
                const f4 pc = *(const f4*)&pb[rb + cl + 4];
                loss4(mc, pc, S4, S5, S6, S7, accb, acci, accu);
            }
        }
        __syncthreads();   // all waves done reading vrow before next overwrite
    }

    // --- block reduction ---
    accb = wave_reduce(accb);
    acci = wave_reduce(acci);
    accu = wave_reduce(accu);
    if (lane == 0) { red[0][wv] = accb; red[1][wv] = acci; red[2][wv] = accu; }
    __syncthreads();
    if (tid == 0) {
        double bt = (double)red[0][0] + red[0][1] + red[0][2] + red[0][3];
        double it2 = (double)red[1][0] + red[1][1] + red[1][2] + red[1][3];
        double ut = (double)red[2][0] + red[2][1] + red[2][2] + red[2][3];
        const size_t pidx = (size_t)img * BPI + tile;
        partials[pidx * 3 + 0] = bt;
        partials[pidx * 3 + 1] = it2;
        partials[pidx * 3 + 2] = ut;
    }
}

// ---------------------------------------------------------------------------
// Finalize from per-block partials (indexed img*BPI + tile), NBLK = 2048.
// ---------------------------------------------------------------------------
__global__ __launch_bounds__(256) void finalize_kernel(const double* __restrict__ partials,
                                                       float* __restrict__ out) {
    __shared__ double redbce[4];
    int tid = threadIdx.x, lane = tid & 63, wv = tid >> 6;

    double bsum = 0.0;
    for (int i = tid; i < NBLK; i += 256) bsum += partials[(size_t)i * 3 + 0];
    #pragma unroll
    for (int off = 32; off; off >>= 1) bsum += __shfl_down(bsum, off, 64);
    if (lane == 0) redbce[wv] = bsum;
    __syncthreads();

    double wiou_term = 0.0;
    if (tid < 64) {
        int bb = tid;
        double it = 0.0, ut = 0.0;
        for (int j = 0; j < BPI; ++j) {
            it += partials[(size_t)(bb * BPI + j) * 3 + 1];
            ut += partials[(size_t)(bb * BPI + j) * 3 + 2];
        }
        wiou_term = 1.0 - (it + 1.0) / (ut - it + 1.0);
    }
    if (wv == 0) {
        #pragma unroll
        for (int off = 32; off; off >>= 1) wiou_term += __shfl_down(wiou_term, off, 64);
    }
    if (tid == 0) {
        double wbce = (redbce[0] + redbce[1] + redbce[2] + redbce[3]) / (double)NELEM;
        out[0] = (float)(wbce + wiou_term * (1.0 / 64.0));
    }
}

// ---------------------------------------------------------------------------
// Fallback path (tiny ws): recompute vertical sums in-kernel + atomics.
// ---------------------------------------------------------------------------
#define ACC_DOUBLES 129
__global__ __launch_bounds__(256) void rowpass_nows_kernel(const float* __restrict__ pred,
                                                           const float* __restrict__ mask,
                                                           double* __restrict__ acc) {
    __shared__ float vrow1[WW];
    __shared__ float red[3][4];
    int b = blockIdx.x / HH;
    int h = blockIdx.x % HH;
    int lo = h - PAD; if (lo < 0) lo = 0;
    int hi = h + PAD; if (hi > HH - 1) hi = HH - 1;
    float s0 = 0.0f, s1 = 0.0f;
    const float* mb = mask + (size_t)b * HH * WW;
    for (int y = lo; y <= hi; ++y) {
        s0 += mb[(size_t)y * WW + threadIdx.x];
        s1 += mb[(size_t)y * WW + threadIdx.x + 256];
    }
    vrow1[threadIdx.x]       = s0;
    vrow1[threadIdx.x + 256] = s1;
    __syncthreads();

    size_t base = ((size_t)b * HH + h) * WW;
    float bce_p = 0.0f, inter_p = 0.0f, uni_p = 0.0f;
    for (int w = threadIdx.x; w < WW; w += 256) {
        int wlo = w - PAD; if (wlo < 0) wlo = 0;
        int whi = w + PAD; if (whi > WW - 1) whi = WW - 1;
        float s = 0.0f;
        for (int k = wlo; k <= whi; ++k) s += vrow1[k];
        float m  = mask[base + w];
        float pr = pred[base + w];
        float weit = 1.0f + 5.0f * fabsf(s * INV_KK - m);
        float e   = expf(-fabsf(pr));
        float bce = fmaxf(pr, 0.0f) - pr * m + log1pf(e);
        float inv = 1.0f / (1.0f + e);
        float p   = (pr >= 0.0f) ? inv : e * inv;
        bce_p += bce; inter_p += p * m * weit; uni_p += (p + m) * weit;
    }
    int lane = threadIdx.x & 63, wvv = threadIdx.x >> 6;
    bce_p = wave_reduce(bce_p); inter_p = wave_reduce(inter_p); uni_p = wave_reduce(uni_p);
    if (lane == 0) { red[0][wvv] = bce_p; red[1][wvv] = inter_p; red[2][wvv] = uni_p; }
    __syncthreads();
    if (threadIdx.x == 0) {
        atomicAdd(&acc[0], (double)(red[0][0] + red[0][1] + red[0][2] + red[0][3]));
        atomicAdd(&acc[1 + b], (double)(red[1][0] + red[1][1] + red[1][2] + red[1][3]));
        atomicAdd(&acc[65 + b], (double)(red[2][0] + red[2][1] + red[2][2] + red[2][3]));
    }
}

__global__ void finalize_atomic_kernel(const double* __restrict__ acc, float* __restrict__ out) {
    int b = threadIdx.x;
    double inter = acc[1 + b];
    double uni   = acc[65 + b];
    double wiou = 1.0 - (inter + 1.0) / (uni - inter + 1.0);
    #pragma unroll
    for (int off = 32; off; off >>= 1) wiou += __shfl_down(wiou, off, 64);
    if (b == 0) {
        double wbce = acc[0] / (double)NELEM;
        out[0] = (float)(wbce + wiou * (1.0 / 64.0));
    }
}

// ---------------------------------------------------------------------------
extern "C" void kernel_launch(void* const* d_in, const int* in_sizes, int n_in,
                              void* d_out, int out_size, void* d_ws, size_t ws_size,
                              hipStream_t stream) {
    const float* pred = (const float*)d_in[0];
    const float* mask = (const float*)d_in[1];
    float* out = (float*)d_out;

    const size_t part_bytes = (size_t)NBLK * 3 * sizeof(double);   // 48 KiB

    if (ws_size >= part_bytes) {
        double* partials = (double*)d_ws;
        fused_kernel<<<NBLK, 256, 0, stream>>>(pred, mask, partials);
        finalize_kernel<<<1, 256, 0, stream>>>(partials, out);
    } else {
        double* acc = (double*)d_ws;
        hipMemsetAsync(acc, 0, ACC_DOUBLES * sizeof(double), stream);
        rowpass_nows_kernel<<<BATCH * HH, 256, 0, stream>>>(pred, mask, acc);
        finalize_atomic_kernel<<<1, 64, 0, stream>>>(acc, out);
    }
}

// Round 10
// 61.633 us; speedup vs baseline: 4.2319x; 1.3228x over previous
//
#include <hip/hip_runtime.h>
#include <math.h>

// Problem constants
#define BATCH 64
#define HH 512
#define WW 512
#define PAD 15
#define NELEM ((size_t)BATCH * HH * WW)
#define INV_KK (1.0f / 961.0f)

#define TILE_H 16              // rows per block (4 iters x 4 rows) -- was 32
#define BPI (HH / TILE_H)      // 32 blocks per image
#define NBLK (BATCH * BPI)     // 2048 blocks -> 8 blocks/CU
#define NXCD 8

typedef float f4 __attribute__((ext_vector_type(4)));

__device__ __forceinline__ float wave_reduce(float v) {
    #pragma unroll
    for (int off = 32; off; off >>= 1) v += __shfl_down(v, off, 64);
    return v;
}

// ---------------------------------------------------------------------------
// Champion structure (round-3, 55.8us, VGPR 36) with occupancy levers only:
//   TILE_H 32->16 (2048 blocks = 8/CU), scan->loss barrier removed (P[wv] is
//   wave-private), outer loop pinned to no-unroll to keep VGPR budget.
// Per 4-row iteration:
//   producer: each thread slides rolling vertical 31-sums for cols (tid,
//             tid+256), writes rows hbase..hbase+3 into vrow     [barrier]
//   scan:     wave wv prefix-scans vrow[wv] (f4 loads, 8-elem local prefix,
//             6-step wave shuffle scan) into P[wv] -- wave-private, no barrier
//   loss:     wave wv, row hbase+wv, lane owns w = lane+64k: S = P[w+15]-
//             P[w-16] (stride-1 LDS, conflict-free), scalar coalesced
//             mask/pred loads, accumulate                        [barrier]
// ---------------------------------------------------------------------------
__global__ __launch_bounds__(256) void fused_kernel(const float* __restrict__ pred,
                                                    const float* __restrict__ mask,
                                                    double* __restrict__ partials) {
    __shared__ float vrow[4][WW];   // 4 vertical-sum rows under construction
    __shared__ float P[4][WW];      // per-wave private prefix rows
    __shared__ float red[3][4];

    // XCD swizzle: xcd = f%8 (HW round-robin); each XCD owns 8 whole images.
    const int f    = blockIdx.x;
    const int xcd  = f & (NXCD - 1);
    const int slot = f >> 3;               // 0..255
    const int img  = xcd * 8 + (slot >> 5);
    const int tile = slot & (BPI - 1);

    const int tid  = threadIdx.x;
    const int lane = tid & 63;
    const int wv   = tid >> 6;
    const int h0   = tile * TILE_H;        // block's first output row (max 496)
    const int c0   = tid;                  // producer columns
    const int c1   = tid + 256;

    const float* mb = mask + (size_t)img * HH * WW;
    const float* pb = pred + (size_t)img * HH * WW;

    // --- init rolling vertical window for row h0: rows [max(0,h0-15), min(511,h0+15)]
    float r0 = 0.0f, r1 = 0.0f;
    {
        int lo = h0 - PAD; if (lo < 0) lo = 0;
        int hi = h0 + PAD; if (hi > HH - 1) hi = HH - 1;   // h0<=496 -> 511, exact fit
        for (int y = lo; y <= hi; ++y) {
            r0 += mb[(size_t)y * WW + c0];
            r1 += mb[(size_t)y * WW + c1];
        }
    }

    float accb = 0.0f, acci = 0.0f, accu = 0.0f;

    #pragma unroll 1   // forbid outer unroll: protects the ~36-VGPR budget
    for (int it = 0; it < TILE_H / 4; ++it) {
        const int hbase = h0 + it * 4;

        // --- producer: emit vertical-sum rows hbase..hbase+3, slide window ---
        #pragma unroll
        for (int j = 0; j < 4; ++j) {
            const int h = hbase + j;
            vrow[j][c0] = r0;
            vrow[j][c1] = r1;
            const int add = h + PAD + 1;
            const int sub = h - PAD;
            float a0 = 0.0f, a1 = 0.0f, s0 = 0.0f, s1 = 0.0f;
            if (add < HH) { a0 = mb[(size_t)add * WW + c0]; a1 = mb[(size_t)add * WW + c1]; }
            if (sub >= 0) { s0 = mb[(size_t)sub * WW + c0]; s1 = mb[(size_t)sub * WW + c1]; }
            r0 += a0 - s0;
            r1 += a1 - s1;
        }
        __syncthreads();   // vrow rows visible to all waves

        // --- scan: wave wv prefix-scans its own row into P[wv] (wave-private) ---
        const int h = hbase + wv;
        const size_t rbase = (size_t)h * WW;

        f4 va = *(const f4*)&vrow[wv][8 * lane];
        f4 vb = *(const f4*)&vrow[wv][8 * lane + 4];
        float p0 = va.x;
        float p1 = p0 + va.y;
        float p2 = p1 + va.z;
        float p3 = p2 + va.w;
        float p4 = p3 + vb.x;
        float p5 = p4 + vb.y;
        float p6 = p5 + vb.z;
        float p7 = p6 + vb.w;
        float lanesum = p7;
        float incl = lanesum;
        #pragma unroll
        for (int off = 1; off < 64; off <<= 1) {
            float n = __shfl_up(incl, off, 64);
            if (lane >= off) incl += n;
        }
        const float excl = incl - lanesum;
        f4 Pa, Pb;
        Pa.x = excl + p0; Pa.y = excl + p1; Pa.z = excl + p2; Pa.w = excl + p3;
        Pb.x = excl + p4; Pb.y = excl + p5; Pb.z = excl + p6; Pb.w = excl + p7;
        *(f4*)&P[wv][8 * lane]     = Pa;
        *(f4*)&P[wv][8 * lane + 4] = Pb;
        // NO barrier: P[wv] is written and read only by wave wv; same-wave DS
        // ordering (+ compiler lgkmcnt) makes it visible without __syncthreads.

        // --- loss: lane owns w = lane + 64k of row hbase+wv ---
        #pragma unroll
        for (int k = 0; k < 8; ++k) {
            const int w = lane + 64 * k;
            int hiw = w + PAD; if (hiw > WW - 1) hiw = WW - 1;
            float s = P[wv][hiw];
            if (w >= PAD + 1) s -= P[wv][w - PAD - 1];

            const float m  = mb[rbase + w];
            const float pr = pb[rbase + w];

            const float weit = 1.0f + 5.0f * fabsf(s * INV_KK - m);
            const float e    = __expf(-fabsf(pr));
            const float bce  = fmaxf(pr, 0.0f) - pr * m + __logf(1.0f + e);
            const float inv  = __builtin_amdgcn_rcpf(1.0f + e);
            const float p    = (pr >= 0.0f) ? inv : e * inv;   // sigmoid(pr)

            accb += bce;
            acci += p * m * weit;
            accu += (p + m) * weit;
        }
        __syncthreads();   // all waves done with vrow before next overwrite
    }

    // --- block reduction ---
    accb = wave_reduce(accb);
    acci = wave_reduce(acci);
    accu = wave_reduce(accu);
    if (lane == 0) { red[0][wv] = accb; red[1][wv] = acci; red[2][wv] = accu; }
    __syncthreads();
    if (tid == 0) {
        double bt = (double)red[0][0] + red[0][1] + red[0][2] + red[0][3];
        double it2 = (double)red[1][0] + red[1][1] + red[1][2] + red[1][3];
        double ut = (double)red[2][0] + red[2][1] + red[2][2] + red[2][3];
        const size_t pidx = (size_t)img * BPI + tile;   // un-swizzled index
        partials[pidx * 3 + 0] = bt;
        partials[pidx * 3 + 1] = it2;
        partials[pidx * 3 + 2] = ut;
    }
}

// ---------------------------------------------------------------------------
// Finalize from per-block partials (indexed img*BPI + tile), NBLK = 2048.
// ---------------------------------------------------------------------------
__global__ __launch_bounds__(256) void finalize_kernel(const double* __restrict__ partials,
                                                       float* __restrict__ out) {
    __shared__ double redbce[4];
    int tid = threadIdx.x, lane = tid & 63, wv = tid >> 6;

    double bsum = 0.0;
    for (int i = tid; i < NBLK; i += 256) bsum += partials[(size_t)i * 3 + 0];
    #pragma unroll
    for (int off = 32; off; off >>= 1) bsum += __shfl_down(bsum, off, 64);
    if (lane == 0) redbce[wv] = bsum;
    __syncthreads();

    double wiou_term = 0.0;
    if (tid < 64) {
        int bb = tid;
        double it = 0.0, ut = 0.0;
        for (int j = 0; j < BPI; ++j) {
            it += partials[(size_t)(bb * BPI + j) * 3 + 1];
            ut += partials[(size_t)(bb * BPI + j) * 3 + 2];
        }
        wiou_term = 1.0 - (it + 1.0) / (ut - it + 1.0);
    }
    if (wv == 0) {
        #pragma unroll
        for (int off = 32; off; off >>= 1) wiou_term += __shfl_down(wiou_term, off, 64);
    }
    if (tid == 0) {
        double wbce = (redbce[0] + redbce[1] + redbce[2] + redbce[3]) / (double)NELEM;
        out[0] = (float)(wbce + wiou_term * (1.0 / 64.0));
    }
}

// ---------------------------------------------------------------------------
// Fallback path (tiny ws): recompute vertical sums in-kernel + atomics.
// ---------------------------------------------------------------------------
#define ACC_DOUBLES 129
__global__ __launch_bounds__(256) void rowpass_nows_kernel(const float* __restrict__ pred,
                                                           const float* __restrict__ mask,
                                                           double* __restrict__ acc) {
    __shared__ float vrow1[WW];
    __shared__ float red[3][4];
    int b = blockIdx.x / HH;
    int h = blockIdx.x % HH;
    int lo = h - PAD; if (lo < 0) lo = 0;
    int hi = h + PAD; if (hi > HH - 1) hi = HH - 1;
    float s0 = 0.0f, s1 = 0.0f;
    const float* mb = mask + (size_t)b * HH * WW;
    for (int y = lo; y <= hi; ++y) {
        s0 += mb[(size_t)y * WW + threadIdx.x];
        s1 += mb[(size_t)y * WW + threadIdx.x + 256];
    }
    vrow1[threadIdx.x]       = s0;
    vrow1[threadIdx.x + 256] = s1;
    __syncthreads();

    size_t base = ((size_t)b * HH + h) * WW;
    float bce_p = 0.0f, inter_p = 0.0f, uni_p = 0.0f;
    for (int w = threadIdx.x; w < WW; w += 256) {
        int wlo = w - PAD; if (wlo < 0) wlo = 0;
        int whi = w + PAD; if (whi > WW - 1) whi = WW - 1;
        float s = 0.0f;
        for (int k = wlo; k <= whi; ++k) s += vrow1[k];
        float m  = mask[base + w];
        float pr = pred[base + w];
        float weit = 1.0f + 5.0f * fabsf(s * INV_KK - m);
        float e   = expf(-fabsf(pr));
        float bce = fmaxf(pr, 0.0f) - pr * m + log1pf(e);
        float inv = 1.0f / (1.0f + e);
        float p   = (pr >= 0.0f) ? inv : e * inv;
        bce_p += bce; inter_p += p * m * weit; uni_p += (p + m) * weit;
    }
    int lane = threadIdx.x & 63, wvv = threadIdx.x >> 6;
    bce_p = wave_reduce(bce_p); inter_p = wave_reduce(inter_p); uni_p = wave_reduce(uni_p);
    if (lane == 0) { red[0][wvv] = bce_p; red[1][wvv] = inter_p; red[2][wvv] = uni_p; }
    __syncthreads();
    if (threadIdx.x == 0) {
        atomicAdd(&acc[0], (double)(red[0][0] + red[0][1] + red[0][2] + red[0][3]));
        atomicAdd(&acc[1 + b], (double)(red[1][0] + red[1][1] + red[1][2] + red[1][3]));
        atomicAdd(&acc[65 + b], (double)(red[2][0] + red[2][1] + red[2][2] + red[2][3]));
    }
}

__global__ void finalize_atomic_kernel(const double* __restrict__ acc, float* __restrict__ out) {
    int b = threadIdx.x;
    double inter = acc[1 + b];
    double uni   = acc[65 + b];
    double wiou = 1.0 - (inter + 1.0) / (uni - inter + 1.0);
    #pragma unroll
    for (int off = 32; off; off >>= 1) wiou += __shfl_down(wiou, off, 64);
    if (b == 0) {
        double wbce = acc[0] / (double)NELEM;
        out[0] = (float)(wbce + wiou * (1.0 / 64.0));
    }
}

// ---------------------------------------------------------------------------
extern "C" void kernel_launch(void* const* d_in, const int* in_sizes, int n_in,
                              void* d_out, int out_size, void* d_ws, size_t ws_size,
                              hipStream_t stream) {
    const float* pred = (const float*)d_in[0];
    const float* mask = (const float*)d_in[1];
    float* out = (float*)d_out;

    const size_t part_bytes = (size_t)NBLK * 3 * sizeof(double);   // 48 KiB

    if (ws_size >= part_bytes) {
        double* partials = (double*)d_ws;
        fused_kernel<<<NBLK, 256, 0, stream>>>(pred, mask, partials);
        finalize_kernel<<<1, 256, 0, stream>>>(partials, out);
    } else {
        double* acc = (double*)d_ws;
        hipMemsetAsync(acc, 0, ACC_DOUBLES * sizeof(double), stream);
        rowpass_nows_kernel<<<BATCH * HH, 256, 0, stream>>>(pred, mask, acc);
        finalize_atomic_kernel<<<1, 64, 0, stream>>>(acc, out);
    }
}

// Round 11
// 51.531 us; speedup vs baseline: 5.0615x; 1.1960x over previous
//
#include <hip/hip_runtime.h>
#include <math.h>

// Problem constants
#define BATCH 64
#define HH 512
#define WW 512
#define PAD 15
#define NELEM ((size_t)BATCH * HH * WW)
#define INV_KK (1.0f / 961.0f)

#define TILE_H 32              // rows per block (8 iters x 4 rows)
#define NIT (TILE_H / 4)       // 8
#define BPI (HH / TILE_H)      // 16 blocks per image
#define NBLK (BATCH * BPI)     // 1024 blocks -> 4 blocks/CU
#define NXCD 8

typedef float f4 __attribute__((ext_vector_type(4)));

__device__ __forceinline__ float wave_reduce(float v) {
    #pragma unroll
    for (int off = 32; off; off >>= 1) v += __shfl_down(v, off, 64);
    return v;
}

// ---------------------------------------------------------------------------
// Champion structure (R3: 55.8us, VGPR 36) + three latency fixes:
//  1. prefetch: iteration it+1's add/sub mask rows are loaded into registers
//     right after it's barrier -> latency hides under it's scan+loss.
//  2. vrow double-buffered (+8KB LDS) -> end-of-loss barrier removed.
//     Safety: a wave reaches it+2's producer (same buffer as it) only after
//     the it+1 barrier, which requires all waves past it's loss.
//  3. scan->loss barrier removed (P[wv] wave-private, R10-validated).
// Net: 1 barrier per 4 rows, producer phase is pure LDS/VALU.
// ---------------------------------------------------------------------------
__global__ __launch_bounds__(256) void fused_kernel(const float* __restrict__ pred,
                                                    const float* __restrict__ mask,
                                                    double* __restrict__ partials) {
    __shared__ float vrow[2][4][WW];   // double-buffered vertical-sum rows
    __shared__ float P[4][WW];         // per-wave private prefix rows
    __shared__ float red[3][4];

    // XCD swizzle: xcd = f%8 (HW round-robin); each XCD owns 8 whole images.
    const int f    = blockIdx.x;
    const int xcd  = f & (NXCD - 1);
    const int slot = f >> 3;               // 0..127
    const int img  = xcd * 8 + (slot >> 4);
    const int tile = slot & (BPI - 1);

    const int tid  = threadIdx.x;
    const int lane = tid & 63;
    const int wv   = tid >> 6;
    const int h0   = tile * TILE_H;        // block's first output row (max 480)
    const int c0   = tid;                  // producer columns
    const int c1   = tid + 256;

    const float* mb = mask + (size_t)img * HH * WW;
    const float* pb = pred + (size_t)img * HH * WW;

    // --- init rolling vertical window for row h0: rows [max(0,h0-15), min(511,h0+15)]
    float r0 = 0.0f, r1 = 0.0f;
    {
        int lo = h0 - PAD; if (lo < 0) lo = 0;
        int hi = h0 + PAD; if (hi > HH - 1) hi = HH - 1;
        for (int y = lo; y <= hi; ++y) {
            r0 += mb[(size_t)y * WW + c0];
            r1 += mb[(size_t)y * WW + c1];
        }
    }

    // Prefetched add/sub rows for the upcoming iteration (rows h+16 / h-15
    // for h = hbase..hbase+3). 16 named registers.
    float pa0, pa1, pa2, pa3, ps0, ps1, ps2, ps3;   // column c0
    float qa0, qa1, qa2, qa3, qs0, qs1, qs2, qs3;   // column c1

    #define PREFETCH(ii)                                                       \
    {                                                                          \
        const int hb = h0 + 4 * (ii);                                          \
        const int a0r = hb + 16, a1r = hb + 17, a2r = hb + 18, a3r = hb + 19;  \
        const int s0r = hb - 15, s1r = hb - 14, s2r = hb - 13, s3r = hb - 12;  \
        pa0 = (a0r < HH) ? mb[(size_t)a0r * WW + c0] : 0.0f;                   \
        pa1 = (a1r < HH) ? mb[(size_t)a1r * WW + c0] : 0.0f;                   \
        pa2 = (a2r < HH) ? mb[(size_t)a2r * WW + c0] : 0.0f;                   \
        pa3 = (a3r < HH) ? mb[(size_t)a3r * WW + c0] : 0.0f;                   \
        ps0 = (s0r >= 0) ? mb[(size_t)s0r * WW + c0] : 0.0f;                   \
        ps1 = (s1r >= 0) ? mb[(size_t)s1r * WW + c0] : 0.0f;                   \
        ps2 = (s2r >= 0) ? mb[(size_t)s2r * WW + c0] : 0.0f;                   \
        ps3 = (s3r >= 0) ? mb[(size_t)s3r * WW + c0] : 0.0f;                   \
        qa0 = (a0r < HH) ? mb[(size_t)a0r * WW + c1] : 0.0f;                   \
        qa1 = (a1r < HH) ? mb[(size_t)a1r * WW + c1] : 0.0f;                   \
        qa2 = (a2r < HH) ? mb[(size_t)a2r * WW + c1] : 0.0f;                   \
        qa3 = (a3r < HH) ? mb[(size_t)a3r * WW + c1] : 0.0f;                   \
        qs0 = (s0r >= 0) ? mb[(size_t)s0r * WW + c1] : 0.0f;                   \
        qs1 = (s1r >= 0) ? mb[(size_t)s1r * WW + c1] : 0.0f;                   \
        qs2 = (s2r >= 0) ? mb[(size_t)s2r * WW + c1] : 0.0f;                   \
        qs3 = (s3r >= 0) ? mb[(size_t)s3r * WW + c1] : 0.0f;                   \
    }

    PREFETCH(0)

    float accb = 0.0f, acci = 0.0f, accu = 0.0f;

    #pragma unroll 1   // forbid outer unroll: protects the register budget
    for (int it = 0; it < NIT; ++it) {
        const int hbase = h0 + it * 4;
        float (*vb)[WW] = vrow[it & 1];

        // --- producer: pure LDS/VALU, consumes prefetched rows ---
        vb[0][c0] = r0; vb[0][c1] = r1; r0 += pa0 - ps0; r1 += qa0 - qs0;
        vb[1][c0] = r0; vb[1][c1] = r1; r0 += pa1 - ps1; r1 += qa1 - qs1;
        vb[2][c0] = r0; vb[2][c1] = r1; r0 += pa2 - ps2; r1 += qa2 - qs2;
        vb[3][c0] = r0; vb[3][c1] = r1; r0 += pa3 - ps3; r1 += qa3 - qs3;
        __syncthreads();   // vb visible to all waves (the only barrier)

        // --- issue next iteration's loads; latency hides under scan+loss ---
        if (it + 1 < NIT) PREFETCH(it + 1)

        // --- scan: wave wv prefix-scans vb[wv] into P[wv] (wave-private) ---
        const int h = hbase + wv;
        const size_t rbase = (size_t)h * WW;

        f4 va = *(const f4*)&vb[wv][8 * lane];
        f4 vbv = *(const f4*)&vb[wv][8 * lane + 4];
        float p0 = va.x;
        float p1 = p0 + va.y;
        float p2 = p1 + va.z;
        float p3 = p2 + va.w;
        float p4 = p3 + vbv.x;
        float p5 = p4 + vbv.y;
        float p6 = p5 + vbv.z;
        float p7 = p6 + vbv.w;
        float lanesum = p7;
        float incl = lanesum;
        #pragma unroll
        for (int off = 1; off < 64; off <<= 1) {
            float n = __shfl_up(incl, off, 64);
            if (lane >= off) incl += n;
        }
        const float excl = incl - lanesum;
        f4 Pa, Pb;
        Pa.x = excl + p0; Pa.y = excl + p1; Pa.z = excl + p2; Pa.w = excl + p3;
        Pb.x = excl + p4; Pb.y = excl + p5; Pb.z = excl + p6; Pb.w = excl + p7;
        *(f4*)&P[wv][8 * lane]     = Pa;
        *(f4*)&P[wv][8 * lane + 4] = Pb;
        // no barrier: P[wv] is wave-private (same-wave DS ordering).

        // --- loss: lane owns w = lane + 64k of row hbase+wv ---
        #pragma unroll
        for (int k = 0; k < 8; ++k) {
            const int w = lane + 64 * k;
            int hiw = w + PAD; if (hiw > WW - 1) hiw = WW - 1;
            float s = P[wv][hiw];
            if (w >= PAD + 1) s -= P[wv][w - PAD - 1];

            const float m  = mb[rbase + w];
            const float pr = pb[rbase + w];

            const float weit = 1.0f + 5.0f * fabsf(s * INV_KK - m);
            const float e    = __expf(-fabsf(pr));
            const float bce  = fmaxf(pr, 0.0f) - pr * m + __logf(1.0f + e);
            const float inv  = __builtin_amdgcn_rcpf(1.0f + e);
            const float p    = (pr >= 0.0f) ? inv : e * inv;   // sigmoid(pr)

            accb += bce;
            acci += p * m * weit;
            accu += (p + m) * weit;
        }
        // no end barrier: vrow is double-buffered (safety argument above).
    }
    #undef PREFETCH

    // --- block reduction ---
    accb = wave_reduce(accb);
    acci = wave_reduce(acci);
    accu = wave_reduce(accu);
    if (lane == 0) { red[0][wv] = accb; red[1][wv] = acci; red[2][wv] = accu; }
    __syncthreads();
    if (tid == 0) {
        double bt = (double)red[0][0] + red[0][1] + red[0][2] + red[0][3];
        double it2 = (double)red[1][0] + red[1][1] + red[1][2] + red[1][3];
        double ut = (double)red[2][0] + red[2][1] + red[2][2] + red[2][3];
        const size_t pidx = (size_t)img * BPI + tile;   // un-swizzled index
        partials[pidx * 3 + 0] = bt;
        partials[pidx * 3 + 1] = it2;
        partials[pidx * 3 + 2] = ut;
    }
}

// ---------------------------------------------------------------------------
// Finalize from per-block partials (indexed img*BPI + tile), NBLK = 1024.
// ---------------------------------------------------------------------------
__global__ __launch_bounds__(256) void finalize_kernel(const double* __restrict__ partials,
                                                       float* __restrict__ out) {
    __shared__ double redbce[4];
    int tid = threadIdx.x, lane = tid & 63, wv = tid >> 6;

    double bsum = 0.0;
    for (int i = tid; i < NBLK; i += 256) bsum += partials[(size_t)i * 3 + 0];
    #pragma unroll
    for (int off = 32; off; off >>= 1) bsum += __shfl_down(bsum, off, 64);
    if (lane == 0) redbce[wv] = bsum;
    __syncthreads();

    double wiou_term = 0.0;
    if (tid < 64) {
        int bb = tid;
        double it = 0.0, ut = 0.0;
        for (int j = 0; j < BPI; ++j) {
            it += partials[(size_t)(bb * BPI + j) * 3 + 1];
            ut += partials[(size_t)(bb * BPI + j) * 3 + 2];
        }
        wiou_term = 1.0 - (it + 1.0) / (ut - it + 1.0);
    }
    if (wv == 0) {
        #pragma unroll
        for (int off = 32; off; off >>= 1) wiou_term += __shfl_down(wiou_term, off, 64);
    }
    if (tid == 0) {
        double wbce = (redbce[0] + redbce[1] + redbce[2] + redbce[3]) / (double)NELEM;
        out[0] = (float)(wbce + wiou_term * (1.0 / 64.0));
    }
}

// ---------------------------------------------------------------------------
// Fallback path (tiny ws): recompute vertical sums in-kernel + atomics.
// ---------------------------------------------------------------------------
#define ACC_DOUBLES 129
__global__ __launch_bounds__(256) void rowpass_nows_kernel(const float* __restrict__ pred,
                                                           const float* __restrict__ mask,
                                                           double* __restrict__ acc) {
    __shared__ float vrow1[WW];
    __shared__ float red[3][4];
    int b = blockIdx.x / HH;
    int h = blockIdx.x % HH;
    int lo = h - PAD; if (lo < 0) lo = 0;
    int hi = h + PAD; if (hi > HH - 1) hi = HH - 1;
    float s0 = 0.0f, s1 = 0.0f;
    const float* mb = mask + (size_t)b * HH * WW;
    for (int y = lo; y <= hi; ++y) {
        s0 += mb[(size_t)y * WW + threadIdx.x];
        s1 += mb[(size_t)y * WW + threadIdx.x + 256];
    }
    vrow1[threadIdx.x]       = s0;
    vrow1[threadIdx.x + 256] = s1;
    __syncthreads();

    size_t base = ((size_t)b * HH + h) * WW;
    float bce_p = 0.0f, inter_p = 0.0f, uni_p = 0.0f;
    for (int w = threadIdx.x; w < WW; w += 256) {
        int wlo = w - PAD; if (wlo < 0) wlo = 0;
        int whi = w + PAD; if (whi > WW - 1) whi = WW - 1;
        float s = 0.0f;
        for (int k = wlo; k <= whi; ++k) s += vrow1[k];
        float m  = mask[base + w];
        float pr = pred[base + w];
        float weit = 1.0f + 5.0f * fabsf(s * INV_KK - m);
        float e   = expf(-fabsf(pr));
        float bce = fmaxf(pr, 0.0f) - pr * m + log1pf(e);
        float inv = 1.0f / (1.0f + e);
        float p   = (pr >= 0.0f) ? inv : e * inv;
        bce_p += bce; inter_p += p * m * weit; uni_p += (p + m) * weit;
    }
    int lane = threadIdx.x & 63, wvv = threadIdx.x >> 6;
    bce_p = wave_reduce(bce_p); inter_p = wave_reduce(inter_p); uni_p = wave_reduce(uni_p);
    if (lane == 0) { red[0][wvv] = bce_p; red[1][wvv] = inter_p; red[2][wvv] = uni_p; }
    __syncthreads();
    if (threadIdx.x == 0) {
        atomicAdd(&acc[0], (double)(red[0][0] + red[0][1] + red[0][2] + red[0][3]));
        atomicAdd(&acc[1 + b], (double)(red[1][0] + red[1][1] + red[1][2] + red[1][3]));
        atomicAdd(&acc[65 + b], (double)(red[2][0] + red[2][1] + red[2][2] + red[2][3]));
    }
}

__global__ void finalize_atomic_kernel(const double* __restrict__ acc, float* __restrict__ out) {
    int b = threadIdx.x;
    double inter = acc[1 + b];
    double uni   = acc[65 + b];
    double wiou = 1.0 - (inter + 1.0) / (uni - inter + 1.0);
    #pragma unroll
    for (int off = 32; off; off >>= 1) wiou += __shfl_down(wiou, off, 64);
    if (b == 0) {
        double wbce = acc[0] / (double)NELEM;
        out[0] = (float)(wbce + wiou * (1.0 / 64.0));
    }
}

// ---------------------------------------------------------------------------
extern "C" void kernel_launch(void* const* d_in, const int* in_sizes, int n_in,
                              void* d_out, int out_size, void* d_ws, size_t ws_size,
                              hipStream_t stream) {
    const float* pred = (const float*)d_in[0];
    const float* mask = (const float*)d_in[1];
    float* out = (float*)d_out;

    const size_t part_bytes = (size_t)NBLK * 3 * sizeof(double);   // 24 KiB

    if (ws_size >= part_bytes) {
        double* partials = (double*)d_ws;
        fused_kernel<<<NBLK, 256, 0, stream>>>(pred, mask, partials);
        finalize_kernel<<<1, 256, 0, stream>>>(partials, out);
    } else {
        double* acc = (double*)d_ws;
        hipMemsetAsync(acc, 0, ACC_DOUBLES * sizeof(double), stream);
        rowpass_nows_kernel<<<BATCH * HH, 256, 0, stream>>>(pred, mask, acc);
        finalize_atomic_kernel<<<1, 64, 0, stream>>>(acc, out);
    }
}